// Round 13
// baseline (247.643 us; speedup 1.0000x reference)
//
#include <hip/hip_runtime.h>
#include <math.h>

#define NPTS 262144
#define RSTR 66    // raw[] row stride in floats (64 pts + 2 pad)

typedef __attribute__((ext_vector_type(4))) float f32x4;
typedef __attribute__((ext_vector_type(8))) short s16x8;

// Exact round-to-nearest-even f32->bf16 (matches numpy/JAX). Do NOT use
// v_cvt_pk_bf16_f32: proven non-RTNE by round-3/4/5 bisection.
__device__ __forceinline__ unsigned short f2bf(float f) {
    union { float f; unsigned u; } v; v.f = f;
    unsigned u = v.u;
    return (unsigned short)((u + 0x7fffu + ((u >> 16) & 1u)) >> 16);
}
__device__ __forceinline__ float bf2f(unsigned short h) {
    union { unsigned u; float f; } v; v.u = ((unsigned)h) << 16;
    return v.f;
}
__device__ __forceinline__ unsigned rnd16(float f) {
    union { float f; unsigned u; } v; v.f = f;
    return v.u + 0x7fffu + ((v.u >> 16) & 1u);
}
__device__ __forceinline__ unsigned packbf(float lo, float hi) {
#if defined(__has_builtin)
#if __has_builtin(__builtin_amdgcn_perm)
    return __builtin_amdgcn_perm(rnd16(hi), rnd16(lo), 0x07060302u);
#else
    return (rnd16(hi) & 0xffff0000u) | (rnd16(lo) >> 16);
#endif
#else
    return (rnd16(hi) & 0xffff0000u) | (rnd16(lo) >> 16);
#endif
}

// Wave-local LDS fence for wave-private producer->consumer chains.
__device__ __forceinline__ void wave_sync() {
    __builtin_amdgcn_sched_barrier(0);
    asm volatile("s_waitcnt lgkmcnt(0)" ::: "memory");
    __builtin_amdgcn_sched_barrier(0);
}

// xfrag element-address swizzle: inject bits 7,8 into bank bits 3,4.
// Only bits >=3 touched -> b128/b32-safe; applied to ALL xfrag accesses.
__device__ __forceinline__ int swz(int e) {
    return e ^ (((e >> 7) & 1) << 3) ^ (((e >> 8) & 1) << 4);
}

// Linear fragment base (bf16-element units): [kt=8][mt=4][lane=64][j=8]
__device__ __forceinline__ int XF(int kt, int mt, int lane) {
    return ((kt * 4 + mt) * 64 + lane) * 8;
}

// A-fragment scatter address (swizzled) for mfma_f32_16x16x32_bf16.
// Lane l holds row p = mt*16 + (l&15), k = kt*32 + 4*(l>>4) + (j&3) + 16*(j>>2).
// CSE identities: fragAddr(p0+i,k) = fragAddr(p0,k) ^ (8*i)  (XOR, not add!);
//                 fragAddr(p,128+j) = fragAddr(p,j) + 8192   (carry-free).
__device__ __forceinline__ int fragAddr(int p, int k) {
    int kt = k >> 5, kk = k & 31;
    int lane = (((kk & 15) >> 2) << 4) | (p & 15);
    int j = ((kk >> 4) << 2) | (kk & 3);
    int mt = (p >> 4) & 3;
    return swz((((kt * 4 + mt) * 64) + lane) * 8 + j);
}

// ---------------------------------------------------------------------------
__global__ void k_deform_vol_t(const float* __restrict__ exp_,
                               const float* __restrict__ bs,
                               const float* __restrict__ mean,
                               float* __restrict__ dvt) {
    int idx = blockIdx.x * blockDim.x + threadIdx.x;   // 262144
    int c = idx & 3;
    int v = (idx >> 2) & 32767;
    int b = idx >> 17;
    float acc = mean[c * 32768 + v];
    #pragma unroll 8
    for (int e = 0; e < 32; ++e)
        acc = fmaf(exp_[b * 32 + e], bs[(e * 4 + c) * 32768 + v], acc);
    dvt[idx] = acc;
}

__global__ void k_ftr(const float* __restrict__ fvol, float* __restrict__ fvt) {
    int i = blockIdx.x * blockDim.x + threadIdx.x;     // 2097152
    int c = i >> 18;
    int v = i & 262143;
    fvt[v * 8 + c] = fvol[i];
}

__global__ void k_hb(const float* __restrict__ exp_,
                     const float* __restrict__ sW1, const float* __restrict__ sb1,
                     const float* __restrict__ cW1, const float* __restrict__ cb1,
                     float* __restrict__ sHb, float* __restrict__ cHb) {
    int b = blockIdx.x;
    int j = threadIdx.x;           // 128
    float a = sb1[j];
    float a2 = cb1[j];
    for (int e = 0; e < 32; ++e) {
        float ev = exp_[b * 32 + e] * (1.0f / 3.0f);
        a  = fmaf(ev, sW1[(216 + e) * 128 + j], a);
        a2 = fmaf(ev, cW1[(243 + e) * 128 + j], a2);
    }
    sHb[b * 128 + j] = a;
    cHb[b * 128 + j] = a2;
}

// ---------------------------------------------------------------------------
// Weight -> B-fragment tables (bf16, optional hi/lo split). Layout [nt][kt].
//  mode 0: identity
//  mode 1 (dW1, K=128): permuted deform K mapping (round-7 derivation)
//  mode 2/3 (sW1/cW1, K=256): permuted feature K mapping
//  mode 4 (sW2/cW2, K=128): H sigma-layout -> h = 32*kt + 16*(kk&1) + (kk>>1)
//    (lets phase 8 write (q0,q1) H pairs as one aligned b32)
// ---------------------------------------------------------------------------
__global__ void k_wprep(const float* __restrict__ src,
                        unsigned short* __restrict__ dhi,
                        unsigned short* __restrict__ dlo,
                        int KT, int Nsrc, int Ksrc, int mode, int total) {
    int i = blockIdx.x * 256 + threadIdx.x;
    if (i >= total) return;
    int j = i & 7, lane = (i >> 3) & 63;
    int tile = i >> 9;
    int kt = tile % KT, nt = tile / KT;
    int n = nt * 16 + (lane & 15);
    int k = kt * 32 + ((lane >> 4) << 2) + (j & 3) + ((j >> 2) << 4);
    int row = -1;
    if (mode == 0) {
        row = (k < Ksrc) ? k : -1;
    } else if (mode == 1) {
        int g = k >> 5, tg = (k >> 4) & 1, r = k & 15;
        if (r < 12) row = 12 + 24 * g + 12 * tg + r;
        else { int idx = (2 * g + tg) * 4 + (r - 12); row = (idx < 12) ? idx : -1; }
    } else if (mode == 4) {
        int kk = k & 31;
        row = (k >> 5) * 32 + ((kk & 1) << 4) + (kk >> 1);
        if (row >= Ksrc) row = -1;
    } else {
        int g = k >> 6, tg = (k >> 5) & 1, r = k & 31;
        if (r < 24) row = 24 + 48 * g + 24 * tg + r;
        else if (r < 27) row = (mode == 3) ? 219 + 6 * g + 3 * tg + (r - 24) : -1;
        else {
            int idx = (2 * g + tg) * 5 + (r - 27);
            if (idx < 24) row = idx;
            else if (idx < 27 && mode == 3) row = 216 + (idx - 24);
            else row = -1;
        }
    }
    float v = (row >= 0 && n < Nsrc) ? src[row * Nsrc + n] : 0.0f;
    unsigned short h = f2bf(v);
    dhi[i] = h;
    if (dlo) dlo[i] = f2bf(v - bf2f(h));
}

// ---------------------------------------------------------------------------
// Axis-factored trilinear gather (channels-last). Per-axis masked weights
// and clamped offsets hoisted out of the corner loop; weight value and
// masking are bit-identical to the per-corner form ((wz*wy)*wx, 0-factor).
// ---------------------------------------------------------------------------
template<int DIM, int NC>
__device__ __forceinline__ void lerp_cl_ax(const float* __restrict__ vol,
                                           int S, int lc,
                                           float px, float py, float pz,
                                           float* __restrict__ o) {
    float fS = (float)S;
    float fx = px * fS - 0.5f;
    float fy = py * fS - 0.5f;
    float fz = pz * fS - 0.5f;
    float x0 = floorf(fx), y0 = floorf(fy), z0 = floorf(fz);
    float wx = fx - x0, wy = fy - y0, wz = fz - z0;
    int ix = (int)x0, iy = (int)y0, iz = (int)z0;
    float wxa[2], wya[2], wza[2];
    int   oxa[2], oya[2], oza[2];
    #pragma unroll
    for (int d = 0; d < 2; ++d) {
        int xi = ix + d, yi = iy + d, zi = iz + d;
        wxa[d] = (xi >= 0 && xi < S) ? (d ? wx : 1.f - wx) : 0.f;
        wya[d] = (yi >= 0 && yi < S) ? (d ? wy : 1.f - wy) : 0.f;
        wza[d] = (zi >= 0 && zi < S) ? (d ? wz : 1.f - wz) : 0.f;
        oxa[d] = (min(max(xi, 0), S - 1) << lc) * NC;
        oya[d] = ((min(max(yi, 0), S - 1) << lc) * DIM) * NC;
        oza[d] = ((min(max(zi, 0), S - 1) << lc) * DIM * DIM) * NC;
    }
    #pragma unroll
    for (int c = 0; c < NC; ++c) o[c] = 0.0f;
    #pragma unroll
    for (int dz = 0; dz < 2; ++dz)
    #pragma unroll
    for (int dy = 0; dy < 2; ++dy) {
        float wzy = wza[dz] * wya[dy];
        int ozy = oza[dz] + oya[dy];
        #pragma unroll
        for (int dx = 0; dx < 2; ++dx) {
            float wgt = wzy * wxa[dx];
            const float4* q = (const float4*)(vol + (size_t)(ozy + oxa[dx]));
            float4 v0 = q[0];
            o[0] = fmaf(v0.x, wgt, o[0]); o[1] = fmaf(v0.y, wgt, o[1]);
            o[2] = fmaf(v0.z, wgt, o[2]); o[3] = fmaf(v0.w, wgt, o[3]);
            if (NC == 8) {
                float4 v1 = q[1];
                o[4] = fmaf(v1.x, wgt, o[4]); o[5] = fmaf(v1.y, wgt, o[5]);
                o[6] = fmaf(v1.z, wgt, o[6]); o[7] = fmaf(v1.w, wgt, o[7]);
            }
        }
    }
}

// channel-major fallback (only used when ws too small for fvt)
template<int DIM, int NC>
__device__ __forceinline__ void lerp_cm_rt(const float* __restrict__ vol,
                                           int S, int lc,
                                           float px, float py, float pz,
                                           float* __restrict__ o) {
    float fS = (float)S;
    float fx = px * fS - 0.5f;
    float fy = py * fS - 0.5f;
    float fz = pz * fS - 0.5f;
    float x0 = floorf(fx), y0 = floorf(fy), z0 = floorf(fz);
    float wx = fx - x0, wy = fy - y0, wz = fz - z0;
    int ix = (int)x0, iy = (int)y0, iz = (int)z0;
    #pragma unroll
    for (int c = 0; c < NC; ++c) o[c] = 0.0f;
    #pragma unroll
    for (int dz = 0; dz < 2; ++dz)
    #pragma unroll
    for (int dy = 0; dy < 2; ++dy)
    #pragma unroll
    for (int dx = 0; dx < 2; ++dx) {
        int xi = ix + dx, yi = iy + dy, zi = iz + dz;
        bool valid = (xi >= 0) & (xi < S) & (yi >= 0) & (yi < S) & (zi >= 0) & (zi < S);
        int xc = min(max(xi, 0), S - 1);
        int yc = min(max(yi, 0), S - 1);
        int zc = min(max(zi, 0), S - 1);
        float wgt = (dz ? wz : 1.f - wz) * (dy ? wy : 1.f - wy) * (dx ? wx : 1.f - wx);
        wgt = valid ? wgt : 0.f;
        int off = ((zc << lc) * DIM + (yc << lc)) * DIM + (xc << lc);
        #pragma unroll
        for (int c = 0; c < NC; ++c)
            o[c] = fmaf(vol[c * (DIM * DIM * DIM) + off], wgt, o[c]);
    }
}

#define MFMA(a, b, c) __builtin_amdgcn_mfma_f32_16x16x32_bf16((a), (b), (c), 0, 0, 0)

// ---------------------------------------------------------------------------
// Main fused kernel: 64 points / block, 4 waves. Hybrid sync (5 barriers +
// wave-local fences on wave-private gather chains). sigma-layout H (mode 4)
// lets phase 8 write b32 pairs. Math bit-exact vs rounds 10/12.
// ---------------------------------------------------------------------------
template<bool CL>
__global__ __launch_bounds__(256, 4) void k_main(
    const float* __restrict__ qp, const float* __restrict__ qv,
    const float* __restrict__ dvt, const float* __restrict__ fvol,
    const float* __restrict__ db1, const float* __restrict__ db2,
    const float* __restrict__ sb2, const float* __restrict__ cb2,
    const float* __restrict__ sHb, const float* __restrict__ cHb,
    const unsigned short* __restrict__ dW1h, const unsigned short* __restrict__ dW1l,
    const unsigned short* __restrict__ sW1h,
    const unsigned short* __restrict__ cW1f,
    const unsigned short* __restrict__ dW2f, const unsigned short* __restrict__ sW2f,
    const unsigned short* __restrict__ cW2f,
    float* __restrict__ out)
{
    __shared__ __align__(16) unsigned short xfrag[16384];    // 32 KB (8 kt)
    __shared__ __align__(16) float raw[28 * RSTR];           // 7.4 KB
    __shared__ float dp[3 * 64];                             // 0.75 KB

    const int t = threadIdx.x;
    const int lane = t & 63;
    const int w = t >> 6;
    const int gp0 = blockIdx.x * 64;
    const int b = gp0 / NPTS;
    const int n0 = gp0 - b * NPTS;
    const float* qpb = qp + b * 3 * NPTS;
    const float* qvb = qv + b * 3 * NPTS;

    const int cc = (lane >> 4) << 2;       // 0,4,8,12
    const int nl = lane & 15;
    const int pp = w * 16 + nl;            // embed point col (wave-private)
    const int lvl = lane >> 4;             // gather: level (3 = aux duty)
    const int pg = w * 16 + nl;            // gather point col (wave-private)

    // ---- Phase 1: deform interp (WAVE-PRIVATE) -> raw rows 0..11; row 12=0 --
    {
        const float* dv = dvt + b * 131072;
        if (lvl < 3) {
            int n = n0 + pg;
            float px = qpb[n], py = qpb[NPTS + n], pz = qpb[2 * NPTS + n];
            float o[4];
            lerp_cl_ax<32, 4>(dv, 32 >> lvl, lvl, px, py, pz, o);
            #pragma unroll
            for (int c = 0; c < 4; ++c) raw[(lvl * 4 + c) * RSTR + pg] = o[c];
        } else {
            raw[12 * RSTR + pg] = 0.f;
        }
    }
    wave_sync();

    // ---- Phase 2: embed deform -> X_d frags (kt 0..3, mt=w, mode-1) ----
    {
        float s0[4], c0[4];
        #pragma unroll
        for (int m = 0; m < 4; ++m) {
            float x = raw[min(cc + m, 12) * RSTR + pp];
            s0[m] = __sinf(x);
            c0[m] = __cosf(x);
        }
        #pragma unroll
        for (int g = 0; g < 4; ++g) {
            float vs[8];
            #pragma unroll
            for (int m = 0; m < 4; ++m) {
                int r = cc + m;
                bool lad = r < 12;
                int i0 = (2 * g) * 4 + (r - 12);
                int i1 = (2 * g + 1) * 4 + (r - 12);
                float r0 = raw[min(max(i0, 0), 12) * RSTR + pp];
                float r1 = raw[min(max(i1, 0), 12) * RSTR + pp];
                vs[m]     = lad ? s0[m] : r0;
                vs[4 + m] = lad ? c0[m] : r1;
            }
            union { unsigned u[4]; s16x8 v; } pk;
            pk.u[0] = packbf(vs[0], vs[1]);
            pk.u[1] = packbf(vs[2], vs[3]);
            pk.u[2] = packbf(vs[4], vs[5]);
            pk.u[3] = packbf(vs[6], vs[7]);
            *(s16x8*)&xfrag[swz(XF(g, w, lane))] = pk.v;
            if (g < 3) {
                #pragma unroll
                for (int m = 0; m < 4; ++m) {
                    float s2 = 2.f * s0[m] * c0[m];
                    float c2 = c0[m] * c0[m] - s0[m] * s0[m];
                    s0[m] = s2; c0[m] = c2;
                }
            }
        }
    }
    __syncthreads();   // all waves' X_d slices complete before cross-wave GEMM

    // ---- Phase 3: dMLP L1 (K=128; nt=w, sweep mt 0..3; hi/lo split) ----
    {
        f32x4 acc[4];
        float bias = db1[w * 16 + nl];
        #pragma unroll
        for (int mt = 0; mt < 4; ++mt) acc[mt] = (f32x4){bias, bias, bias, bias};
        #pragma unroll 1
        for (int kt = 0; kt < 4; ++kt) {
            s16x8 bh = *(const s16x8*)&dW1h[((w * 4 + kt) * 64 + lane) * 8];
            s16x8 bl = *(const s16x8*)&dW1l[((w * 4 + kt) * 64 + lane) * 8];
            #pragma unroll
            for (int mt = 0; mt < 4; ++mt) {
                s16x8 a = *(const s16x8*)&xfrag[swz(XF(kt, mt, lane))];
                acc[mt] = MFMA(a, bh, acc[mt]);
                acc[mt] = MFMA(a, bl, acc[mt]);
            }
        }
        // relu -> H_d frags (kt 4..5, disjoint from X_d kt 0..3)
        int j = w * 16 + nl;
        #pragma unroll
        for (int mt = 0; mt < 4; ++mt) {
            int a0 = fragAddr(mt * 16 + cc, 128 + j);
            #pragma unroll
            for (int i = 0; i < 4; ++i)
                xfrag[a0 ^ (8 * i)] = f2bf(fmaxf(acc[mt][i], 0.f));
        }
    }
    __syncthreads();   // all waves' H_d j-columns complete before ph4 reads

    // ---- Phase 4: dMLP L2 (K=64, H_d at kt 4..5; mt=w -> own points) ----
    {
        f32x4 acc = (f32x4){0, 0, 0, 0};
        #pragma unroll
        for (int kt = 0; kt < 2; ++kt) {
            s16x8 bb = *(const s16x8*)&dW2f[(kt * 64 + lane) * 8];
            s16x8 a = *(const s16x8*)&xfrag[swz(XF(4 + kt, w, lane))];
            acc = MFMA(a, bb, acc);
        }
        int col = nl;
        if (col < 3) {
            #pragma unroll
            for (int i = 0; i < 4; ++i) {
                int p = w * 16 + cc + i;
                float v = acc[i] + db2[col];
                out[(b * 3 + col) * NPTS + n0 + p] = v;
                dp[col * 64 + p] = fmaf(v, 0.1f, qpb[col * NPTS + n0 + p]);
            }
        }
    }
    wave_sync();   // dp for wave-own points only -> wave-local fence suffices

    // ---- Phase 5: feature interp (WAVE-PRIVATE); viewdir on lvl==3 lanes ---
    {
        if (lvl < 3) {
            float px = dp[pg], py = dp[64 + pg], pz = dp[128 + pg];
            float o[8];
            if (CL) lerp_cl_ax<64, 8>(fvol, 64 >> lvl, lvl, px, py, pz, o);
            else    lerp_cm_rt<64, 8>(fvol, 64 >> lvl, lvl, px, py, pz, o);
            #pragma unroll
            for (int c = 0; c < 8; ++c) raw[(lvl * 8 + c) * RSTR + pg] = o[c];
        } else {
            int n = n0 + pg;
            raw[24 * RSTR + pg] = qvb[n];
            raw[25 * RSTR + pg] = qvb[NPTS + n];
            raw[26 * RSTR + pg] = qvb[2 * NPTS + n];
            raw[27 * RSTR + pg] = 0.f;
        }
    }
    wave_sync();

    // ---- Phase 6: embed feature+view -> X frags (kt 0..7, mt=w, mode-2/3) --
    {
        float sL[4], cL[4], sH[4], cH[4];
        #pragma unroll
        for (int m = 0; m < 4; ++m) {
            float xl = raw[(cc + m) * RSTR + pp];
            sL[m] = __sinf(xl); cL[m] = __cosf(xl);
            float xh = raw[min(16 + cc + m, 27) * RSTR + pp];
            sH[m] = __sinf(xh); cH[m] = __cosf(xh);
        }
        #pragma unroll
        for (int g = 0; g < 4; ++g) {
            #pragma unroll
            for (int tg = 0; tg < 2; ++tg) {
                float vs[8];
                #pragma unroll
                for (int m = 0; m < 4; ++m) {
                    vs[m] = tg ? cL[m] : sL[m];
                    int rh = 16 + cc + m;
                    int idx = (2 * g + tg) * 5 + (rh - 27);
                    float rsv = raw[min(max(idx, 0), 27) * RSTR + pp];
                    float lad = tg ? cH[m] : sH[m];
                    vs[4 + m] = (rh < 27) ? lad : rsv;
                }
                union { unsigned u[4]; s16x8 v; } pk;
                pk.u[0] = packbf(vs[0], vs[1]);
                pk.u[1] = packbf(vs[2], vs[3]);
                pk.u[2] = packbf(vs[4], vs[5]);
                pk.u[3] = packbf(vs[6], vs[7]);
                *(s16x8*)&xfrag[swz(XF(2 * g + tg, w, lane))] = pk.v;
            }
            if (g < 3) {
                #pragma unroll
                for (int m = 0; m < 4; ++m) {
                    float s2 = 2.f * sL[m] * cL[m];
                    float c2 = cL[m] * cL[m] - sL[m] * sL[m];
                    sL[m] = s2; cL[m] = c2;
                    float s3 = 2.f * sH[m] * cH[m];
                    float c3 = cH[m] * cH[m] - sH[m] * sH[m];
                    sH[m] = s3; cH[m] = c3;
                }
            }
        }
    }
    __syncthreads();   // all waves' X slices complete before cross-wave GEMM

    // ---- Phase 7: density L1 (single bf16) + color L1 (nt pair = 2w,2w+1) --
    f32x4 accs[4][2], accc[4][2];
    {
        #pragma unroll
        for (int q = 0; q < 2; ++q) {
            float bsv = sHb[b * 128 + (2 * w + q) * 16 + nl];
            float bcv = cHb[b * 128 + (2 * w + q) * 16 + nl];
            #pragma unroll
            for (int mt = 0; mt < 4; ++mt) {
                accs[mt][q] = (f32x4){bsv, bsv, bsv, bsv};
                accc[mt][q] = (f32x4){bcv, bcv, bcv, bcv};
            }
        }
        #pragma unroll 1
        for (int kt = 0; kt < 8; ++kt) {
            s16x8 bh0 = *(const s16x8*)&sW1h[(((2 * w    ) * 8 + kt) * 64 + lane) * 8];
            s16x8 bh1 = *(const s16x8*)&sW1h[(((2 * w + 1) * 8 + kt) * 64 + lane) * 8];
            #pragma unroll
            for (int mt = 0; mt < 4; ++mt) {
                s16x8 a = *(const s16x8*)&xfrag[swz(XF(kt, mt, lane))];
                accs[mt][0] = MFMA(a, bh0, accs[mt][0]);
                accs[mt][1] = MFMA(a, bh1, accs[mt][1]);
            }
        }
        #pragma unroll 1
        for (int kt = 0; kt < 8; ++kt) {
            s16x8 b0 = *(const s16x8*)&cW1f[(((2 * w    ) * 8 + kt) * 64 + lane) * 8];
            s16x8 b1 = *(const s16x8*)&cW1f[(((2 * w + 1) * 8 + kt) * 64 + lane) * 8];
            #pragma unroll
            for (int mt = 0; mt < 4; ++mt) {
                s16x8 a = *(const s16x8*)&xfrag[swz(XF(kt, mt, lane))];
                accc[mt][0] = MFMA(a, b0, accc[mt][0]);
                accc[mt][1] = MFMA(a, b1, accc[mt][1]);
            }
        }
    }
    __syncthreads();   // all X reads done before H overwrites the same region

    // ---- Phase 8: relu -> H_s (kt 0..3) + H_c (kt 4..7), PAIRED b32 writes --
    // sigma layout: h=(2w+q)*16+nl lives at kt=w, kk=2*nl+q -> (q0,q1) are
    // consecutive aligned j-elements of the same fragment. Derivation checked
    // against fragAddr; swz keeps pairs adjacent (bits>=3 only); i-step is
    // XOR(8i) (bits 3,4 of base are 0 since cc&3==0).
    {
        const int jbase = ((nl >> 3) << 2) + ((nl & 1) << 1);
        const int lbase = ((nl & 7) >> 1) * 16 + cc;
        #pragma unroll
        for (int mt = 0; mt < 4; ++mt) {
            int a0 = swz((((w * 4 + mt) * 64) + lbase) * 8 + jbase);
            #pragma unroll
            for (int i = 0; i < 4; ++i) {
                int ai = a0 ^ (8 * i);
                float s0v = fmaxf(accs[mt][0][i], 0.f);
                float s1v = fmaxf(accs[mt][1][i], 0.f);
                float c0v = fmaxf(accc[mt][0][i], 0.f);
                float c1v = fmaxf(accc[mt][1][i], 0.f);
                *(unsigned*)&xfrag[ai]        = packbf(s0v, s1v);
                *(unsigned*)&xfrag[ai + 8192] = packbf(c0v, c1v);
            }
        }
    }
    __syncthreads();

    // ---- Phase 9: density L2 + color L2 (K=128 each; mt=w -> own points) ---
    {
        f32x4 as = (f32x4){0, 0, 0, 0};
        f32x4 ac = (f32x4){0, 0, 0, 0};
        #pragma unroll
        for (int kt = 0; kt < 4; ++kt) {
            s16x8 bsv = *(const s16x8*)&sW2f[(kt * 64 + lane) * 8];
            s16x8 bcv = *(const s16x8*)&cW2f[(kt * 64 + lane) * 8];
            s16x8 a1 = *(const s16x8*)&xfrag[swz(XF(kt, w, lane))];
            s16x8 a2 = *(const s16x8*)&xfrag[swz(XF(4 + kt, w, lane))];
            as = MFMA(a1, bsv, as);
            ac = MFMA(a2, bcv, ac);
        }
        int col = nl;
        #pragma unroll
        for (int i = 0; i < 4; ++i) {
            int p = w * 16 + cc + i;
            if (col == 0)
                out[6 * NPTS + b * NPTS + n0 + p] = as[i] + sb2[0];
            if (col < 3) {
                float v = ac[i] + cb2[col];
                out[8 * NPTS + (b * 3 + col) * NPTS + n0 + p] =
                    1.f / (1.f + __expf(-v));
            }
        }
    }
}

// ---------------------------------------------------------------------------
extern "C" void kernel_launch(void* const* d_in, const int* in_sizes, int n_in,
                              void* d_out, int out_size, void* d_ws, size_t ws_size,
                              hipStream_t stream) {
    const float* qp   = (const float*)d_in[0];
    const float* qv   = (const float*)d_in[1];
    const float* exp_ = (const float*)d_in[2];
    const float* bs   = (const float*)d_in[3];
    const float* mean = (const float*)d_in[4];
    const float* fvol = (const float*)d_in[5];
    const float* dW1  = (const float*)d_in[6];
    const float* db1  = (const float*)d_in[7];
    const float* dW2  = (const float*)d_in[8];
    const float* db2  = (const float*)d_in[9];
    const float* sW1  = (const float*)d_in[10];
    const float* sb1  = (const float*)d_in[11];
    const float* sW2  = (const float*)d_in[12];
    const float* sb2  = (const float*)d_in[13];
    const float* cW1  = (const float*)d_in[14];
    const float* cb1  = (const float*)d_in[15];
    const float* cW2  = (const float*)d_in[16];
    const float* cb2  = (const float*)d_in[17];

    float* out = (float*)d_out;
    float* ws  = (float*)d_ws;

    float* dvt = ws;                                   // 262144 f
    float* sHb = ws + 262144;                          // 256 f
    float* cHb = ws + 262400;                          // 256 f
    unsigned short* wb = (unsigned short*)(ws + 262656);
    unsigned short* dW1h  = wb;                        // 8192
    unsigned short* dW1l  = wb + 8192;                 // 8192
    unsigned short* sW1h  = wb + 16384;                // 32768
    unsigned short* cW1f_ = wb + 49152;                // 32768
    unsigned short* dW2f  = wb + 81920;                // 1024
    unsigned short* sW2f  = wb + 82944;                // 2048
    unsigned short* cW2f  = wb + 84992;                // 2048 (end 87040 u16)
    float* fvt = ws + 262656 + 43520;                  // = ws + 306176
    bool cl = ws_size >= (size_t)(306176 + 2097152) * 4;

    k_deform_vol_t<<<1024, 256, 0, stream>>>(exp_, bs, mean, dvt);
    k_hb<<<2, 128, 0, stream>>>(exp_, sW1, sb1, cW1, cb1, sHb, cHb);
    k_wprep<<<32, 256, 0, stream>>>(dW1, dW1h, dW1l, 4, 64, 128, 1, 8192);
    k_wprep<<<128, 256, 0, stream>>>(sW1, sW1h, nullptr, 8, 128, 256, 2, 32768);
    k_wprep<<<128, 256, 0, stream>>>(cW1, cW1f_, nullptr, 8, 128, 256, 3, 32768);
    k_wprep<<<4, 256, 0, stream>>>(dW2, dW2f, nullptr, 2, 3, 64, 0, 1024);
    k_wprep<<<8, 256, 0, stream>>>(sW2, sW2f, nullptr, 4, 1, 128, 4, 2048);
    k_wprep<<<8, 256, 0, stream>>>(cW2, cW2f, nullptr, 4, 3, 128, 4, 2048);

    if (cl) {
        k_ftr<<<2097152 / 256, 256, 0, stream>>>(fvol, fvt);
        k_main<true><<<8192, 256, 0, stream>>>(
            qp, qv, dvt, fvt, db1, db2, sb2, cb2, sHb, cHb,
            dW1h, dW1l, sW1h, cW1f_, dW2f, sW2f, cW2f, out);
    } else {
        k_main<false><<<8192, 256, 0, stream>>>(
            qp, qv, dvt, fvol, db1, db2, sb2, cb2, sHb, cHb,
            dW1h, dW1l, sW1h, cW1f_, dW2f, sW2f, cW2f, out);
    }
}

// Round 14
// 211.108 us; speedup vs baseline: 1.1731x; 1.1731x over previous
//
#include <hip/hip_runtime.h>
#include <math.h>

#define NPTS 262144
#define RSTR 66    // raw[] row stride in floats (64 pts + 2 pad)

typedef __attribute__((ext_vector_type(4))) float f32x4;
typedef __attribute__((ext_vector_type(8))) short s16x8;

// Exact round-to-nearest-even f32->bf16 (matches numpy/JAX). Do NOT use
// v_cvt_pk_bf16_f32: proven non-RTNE by round-3/4/5 bisection.
__device__ __forceinline__ unsigned short f2bf(float f) {
    union { float f; unsigned u; } v; v.f = f;
    unsigned u = v.u;
    return (unsigned short)((u + 0x7fffu + ((u >> 16) & 1u)) >> 16);
}
__device__ __forceinline__ float bf2f(unsigned short h) {
    union { unsigned u; float f; } v; v.u = ((unsigned)h) << 16;
    return v.f;
}
__device__ __forceinline__ unsigned rnd16(float f) {
    union { float f; unsigned u; } v; v.f = f;
    return v.u + 0x7fffu + ((v.u >> 16) & 1u);
}
__device__ __forceinline__ unsigned packbf(float lo, float hi) {
#if defined(__has_builtin)
#if __has_builtin(__builtin_amdgcn_perm)
    return __builtin_amdgcn_perm(rnd16(hi), rnd16(lo), 0x07060302u);
#else
    return (rnd16(hi) & 0xffff0000u) | (rnd16(lo) >> 16);
#endif
#else
    return (rnd16(hi) & 0xffff0000u) | (rnd16(lo) >> 16);
#endif
}

// Wave-local LDS fence for wave-private producer->consumer chains.
__device__ __forceinline__ void wave_sync() {
    __builtin_amdgcn_sched_barrier(0);
    asm volatile("s_waitcnt lgkmcnt(0)" ::: "memory");
    __builtin_amdgcn_sched_barrier(0);
}

// xfrag element-address swizzle: inject bits 7,8 into bank bits 3,4.
// Only bits >=3 touched -> b128/b32-safe; applied to ALL xfrag accesses.
__device__ __forceinline__ int swz(int e) {
    return e ^ (((e >> 7) & 1) << 3) ^ (((e >> 8) & 1) << 4);
}

// Linear fragment base (bf16-element units): [kt=8][mt=4][lane=64][j=8]
__device__ __forceinline__ int XF(int kt, int mt, int lane) {
    return ((kt * 4 + mt) * 64 + lane) * 8;
}

// A-fragment scatter address (swizzled) for mfma_f32_16x16x32_bf16.
// Lane l holds row p = mt*16 + (l&15), k = kt*32 + 4*(l>>4) + (j&3) + 16*(j>>2).
// CSE identities: fragAddr(p0+i,k) = fragAddr(p0,k) ^ (8*i)  (XOR, not add!);
//                 fragAddr(p,128+j) = fragAddr(p,j) + 8192   (carry-free).
__device__ __forceinline__ int fragAddr(int p, int k) {
    int kt = k >> 5, kk = k & 31;
    int lane = (((kk & 15) >> 2) << 4) | (p & 15);
    int j = ((kk >> 4) << 2) | (kk & 3);
    int mt = (p >> 4) & 3;
    return swz((((kt * 4 + mt) * 64) + lane) * 8 + j);
}

// ---------------------------------------------------------------------------
__global__ void k_deform_vol_t(const float* __restrict__ exp_,
                               const float* __restrict__ bs,
                               const float* __restrict__ mean,
                               float* __restrict__ dvt) {
    int idx = blockIdx.x * blockDim.x + threadIdx.x;   // 262144
    int c = idx & 3;
    int v = (idx >> 2) & 32767;
    int b = idx >> 17;
    float acc = mean[c * 32768 + v];
    #pragma unroll 8
    for (int e = 0; e < 32; ++e)
        acc = fmaf(exp_[b * 32 + e], bs[(e * 4 + c) * 32768 + v], acc);
    dvt[idx] = acc;
}

// feature volume transpose + bf16 quantize: fvt[v][c] = bf16(fvol[c][v]).
// bf16 (4 MB) keeps the whole volume L2-resident per XCD -> gather hits L2
// (~200cy) instead of HBM (~900cy), and one s16x8 load covers all 8 channels.
__global__ void k_ftr_bf(const float* __restrict__ fvol,
                         unsigned short* __restrict__ fvt) {
    int i = blockIdx.x * blockDim.x + threadIdx.x;     // 2097152
    int c = i >> 18;
    int v = i & 262143;
    fvt[v * 8 + c] = f2bf(fvol[i]);
}

__global__ void k_hb(const float* __restrict__ exp_,
                     const float* __restrict__ sW1, const float* __restrict__ sb1,
                     const float* __restrict__ cW1, const float* __restrict__ cb1,
                     float* __restrict__ sHb, float* __restrict__ cHb) {
    int b = blockIdx.x;
    int j = threadIdx.x;           // 128
    float a = sb1[j];
    float a2 = cb1[j];
    for (int e = 0; e < 32; ++e) {
        float ev = exp_[b * 32 + e] * (1.0f / 3.0f);
        a  = fmaf(ev, sW1[(216 + e) * 128 + j], a);
        a2 = fmaf(ev, cW1[(243 + e) * 128 + j], a2);
    }
    sHb[b * 128 + j] = a;
    cHb[b * 128 + j] = a2;
}

// ---------------------------------------------------------------------------
// Weight -> B-fragment tables (bf16, optional hi/lo split). Layout [nt][kt].
//  mode 0: identity
//  mode 1 (dW1, K=128): permuted deform K mapping (round-7 derivation)
//  mode 2/3 (sW1/cW1, K=256): permuted feature K mapping
//  mode 4 (sW2/cW2, K=128): H sigma-layout -> h = 32*kt + 16*(kk&1) + (kk>>1)
// ---------------------------------------------------------------------------
__global__ void k_wprep(const float* __restrict__ src,
                        unsigned short* __restrict__ dhi,
                        unsigned short* __restrict__ dlo,
                        int KT, int Nsrc, int Ksrc, int mode, int total) {
    int i = blockIdx.x * 256 + threadIdx.x;
    if (i >= total) return;
    int j = i & 7, lane = (i >> 3) & 63;
    int tile = i >> 9;
    int kt = tile % KT, nt = tile / KT;
    int n = nt * 16 + (lane & 15);
    int k = kt * 32 + ((lane >> 4) << 2) + (j & 3) + ((j >> 2) << 4);
    int row = -1;
    if (mode == 0) {
        row = (k < Ksrc) ? k : -1;
    } else if (mode == 1) {
        int g = k >> 5, tg = (k >> 4) & 1, r = k & 15;
        if (r < 12) row = 12 + 24 * g + 12 * tg + r;
        else { int idx = (2 * g + tg) * 4 + (r - 12); row = (idx < 12) ? idx : -1; }
    } else if (mode == 4) {
        int kk = k & 31;
        row = (k >> 5) * 32 + ((kk & 1) << 4) + (kk >> 1);
        if (row >= Ksrc) row = -1;
    } else {
        int g = k >> 6, tg = (k >> 5) & 1, r = k & 31;
        if (r < 24) row = 24 + 48 * g + 24 * tg + r;
        else if (r < 27) row = (mode == 3) ? 219 + 6 * g + 3 * tg + (r - 24) : -1;
        else {
            int idx = (2 * g + tg) * 5 + (r - 27);
            if (idx < 24) row = idx;
            else if (idx < 27 && mode == 3) row = 216 + (idx - 24);
            else row = -1;
        }
    }
    float v = (row >= 0 && n < Nsrc) ? src[row * Nsrc + n] : 0.0f;
    unsigned short h = f2bf(v);
    dhi[i] = h;
    if (dlo) dlo[i] = f2bf(v - bf2f(h));
}

// ---------------------------------------------------------------------------
// Axis-factored trilinear gather, f32 channels-last (deform volume).
// ---------------------------------------------------------------------------
template<int DIM, int NC>
__device__ __forceinline__ void lerp_cl_ax(const float* __restrict__ vol,
                                           int S, int lc,
                                           float px, float py, float pz,
                                           float* __restrict__ o) {
    float fS = (float)S;
    float fx = px * fS - 0.5f;
    float fy = py * fS - 0.5f;
    float fz = pz * fS - 0.5f;
    float x0 = floorf(fx), y0 = floorf(fy), z0 = floorf(fz);
    float wx = fx - x0, wy = fy - y0, wz = fz - z0;
    int ix = (int)x0, iy = (int)y0, iz = (int)z0;
    float wxa[2], wya[2], wza[2];
    int   oxa[2], oya[2], oza[2];
    #pragma unroll
    for (int d = 0; d < 2; ++d) {
        int xi = ix + d, yi = iy + d, zi = iz + d;
        wxa[d] = (xi >= 0 && xi < S) ? (d ? wx : 1.f - wx) : 0.f;
        wya[d] = (yi >= 0 && yi < S) ? (d ? wy : 1.f - wy) : 0.f;
        wza[d] = (zi >= 0 && zi < S) ? (d ? wz : 1.f - wz) : 0.f;
        oxa[d] = (min(max(xi, 0), S - 1) << lc) * NC;
        oya[d] = ((min(max(yi, 0), S - 1) << lc) * DIM) * NC;
        oza[d] = ((min(max(zi, 0), S - 1) << lc) * DIM * DIM) * NC;
    }
    #pragma unroll
    for (int c = 0; c < NC; ++c) o[c] = 0.0f;
    #pragma unroll
    for (int dz = 0; dz < 2; ++dz)
    #pragma unroll
    for (int dy = 0; dy < 2; ++dy) {
        float wzy = wza[dz] * wya[dy];
        int ozy = oza[dz] + oya[dy];
        #pragma unroll
        for (int dx = 0; dx < 2; ++dx) {
            float wgt = wzy * wxa[dx];
            const float4* q = (const float4*)(vol + (size_t)(ozy + oxa[dx]));
            float4 v0 = q[0];
            o[0] = fmaf(v0.x, wgt, o[0]); o[1] = fmaf(v0.y, wgt, o[1]);
            o[2] = fmaf(v0.z, wgt, o[2]); o[3] = fmaf(v0.w, wgt, o[3]);
            if (NC == 8) {
                float4 v1 = q[1];
                o[4] = fmaf(v1.x, wgt, o[4]); o[5] = fmaf(v1.y, wgt, o[5]);
                o[6] = fmaf(v1.z, wgt, o[6]); o[7] = fmaf(v1.w, wgt, o[7]);
            }
        }
    }
}

// Axis-factored trilinear gather over the bf16 channels-last feature volume.
// One s16x8 (16 B) load per corner covers all 8 channels.
__device__ __forceinline__ void lerp_bf_ax64(const unsigned short* __restrict__ vol,
                                             int S, int lc,
                                             float px, float py, float pz,
                                             float* __restrict__ o) {
    const int DIM = 64, NC = 8;
    float fS = (float)S;
    float fx = px * fS - 0.5f;
    float fy = py * fS - 0.5f;
    float fz = pz * fS - 0.5f;
    float x0 = floorf(fx), y0 = floorf(fy), z0 = floorf(fz);
    float wx = fx - x0, wy = fy - y0, wz = fz - z0;
    int ix = (int)x0, iy = (int)y0, iz = (int)z0;
    float wxa[2], wya[2], wza[2];
    int   oxa[2], oya[2], oza[2];
    #pragma unroll
    for (int d = 0; d < 2; ++d) {
        int xi = ix + d, yi = iy + d, zi = iz + d;
        wxa[d] = (xi >= 0 && xi < S) ? (d ? wx : 1.f - wx) : 0.f;
        wya[d] = (yi >= 0 && yi < S) ? (d ? wy : 1.f - wy) : 0.f;
        wza[d] = (zi >= 0 && zi < S) ? (d ? wz : 1.f - wz) : 0.f;
        oxa[d] = (min(max(xi, 0), S - 1) << lc) * NC;
        oya[d] = ((min(max(yi, 0), S - 1) << lc) * DIM) * NC;
        oza[d] = ((min(max(zi, 0), S - 1) << lc) * DIM * DIM) * NC;
    }
    #pragma unroll
    for (int c = 0; c < NC; ++c) o[c] = 0.0f;
    #pragma unroll
    for (int dz = 0; dz < 2; ++dz)
    #pragma unroll
    for (int dy = 0; dy < 2; ++dy) {
        float wzy = wza[dz] * wya[dy];
        int ozy = oza[dz] + oya[dy];
        #pragma unroll
        for (int dx = 0; dx < 2; ++dx) {
            float wgt = wzy * wxa[dx];
            union { s16x8 v; unsigned short s[8]; } q;
            q.v = *(const s16x8*)(vol + (size_t)(ozy + oxa[dx]));
            #pragma unroll
            for (int c = 0; c < NC; ++c)
                o[c] = fmaf(bf2f(q.s[c]), wgt, o[c]);
        }
    }
}

// channel-major f32 fallback (only used when ws too small for fvt)
template<int DIM, int NC>
__device__ __forceinline__ void lerp_cm_rt(const float* __restrict__ vol,
                                           int S, int lc,
                                           float px, float py, float pz,
                                           float* __restrict__ o) {
    float fS = (float)S;
    float fx = px * fS - 0.5f;
    float fy = py * fS - 0.5f;
    float fz = pz * fS - 0.5f;
    float x0 = floorf(fx), y0 = floorf(fy), z0 = floorf(fz);
    float wx = fx - x0, wy = fy - y0, wz = fz - z0;
    int ix = (int)x0, iy = (int)y0, iz = (int)z0;
    #pragma unroll
    for (int c = 0; c < NC; ++c) o[c] = 0.0f;
    #pragma unroll
    for (int dz = 0; dz < 2; ++dz)
    #pragma unroll
    for (int dy = 0; dy < 2; ++dy)
    #pragma unroll
    for (int dx = 0; dx < 2; ++dx) {
        int xi = ix + dx, yi = iy + dy, zi = iz + dz;
        bool valid = (xi >= 0) & (xi < S) & (yi >= 0) & (yi < S) & (zi >= 0) & (zi < S);
        int xc = min(max(xi, 0), S - 1);
        int yc = min(max(yi, 0), S - 1);
        int zc = min(max(zi, 0), S - 1);
        float wgt = (dz ? wz : 1.f - wz) * (dy ? wy : 1.f - wy) * (dx ? wx : 1.f - wx);
        wgt = valid ? wgt : 0.f;
        int off = ((zc << lc) * DIM + (yc << lc)) * DIM + (xc << lc);
        #pragma unroll
        for (int c = 0; c < NC; ++c)
            o[c] = fmaf(vol[c * (DIM * DIM * DIM) + off], wgt, o[c]);
    }
}

#define MFMA(a, b, c) __builtin_amdgcn_mfma_f32_16x16x32_bf16((a), (b), (c), 0, 0, 0)

// ---------------------------------------------------------------------------
// Main fused kernel: 64 points / block, 4 waves. Hybrid sync (5 barriers +
// wave-local fences on wave-private gather chains). bf16 feature volume
// (L2-resident) for the latency-critical gather. Math otherwise identical
// to rounds 12/13.
// ---------------------------------------------------------------------------
template<bool CL>
__global__ __launch_bounds__(256, 4) void k_main(
    const float* __restrict__ qp, const float* __restrict__ qv,
    const float* __restrict__ dvt,
    const unsigned short* __restrict__ fvt, const float* __restrict__ fvol,
    const float* __restrict__ db1, const float* __restrict__ db2,
    const float* __restrict__ sb2, const float* __restrict__ cb2,
    const float* __restrict__ sHb, const float* __restrict__ cHb,
    const unsigned short* __restrict__ dW1h, const unsigned short* __restrict__ dW1l,
    const unsigned short* __restrict__ sW1h,
    const unsigned short* __restrict__ cW1f,
    const unsigned short* __restrict__ dW2f, const unsigned short* __restrict__ sW2f,
    const unsigned short* __restrict__ cW2f,
    float* __restrict__ out)
{
    __shared__ __align__(16) unsigned short xfrag[16384];    // 32 KB (8 kt)
    __shared__ __align__(16) float raw[28 * RSTR];           // 7.4 KB
    __shared__ float dp[3 * 64];                             // 0.75 KB

    const int t = threadIdx.x;
    const int lane = t & 63;
    const int w = t >> 6;
    const int gp0 = blockIdx.x * 64;
    const int b = gp0 / NPTS;
    const int n0 = gp0 - b * NPTS;
    const float* qpb = qp + b * 3 * NPTS;
    const float* qvb = qv + b * 3 * NPTS;

    const int cc = (lane >> 4) << 2;       // 0,4,8,12
    const int nl = lane & 15;
    const int pp = w * 16 + nl;            // embed point col (wave-private)
    const int lvl = lane >> 4;             // gather: level (3 = aux duty)
    const int pg = w * 16 + nl;            // gather point col (wave-private)

    // ---- Phase 1: deform interp (WAVE-PRIVATE) -> raw rows 0..11; row 12=0 --
    {
        const float* dv = dvt + b * 131072;
        if (lvl < 3) {
            int n = n0 + pg;
            float px = qpb[n], py = qpb[NPTS + n], pz = qpb[2 * NPTS + n];
            float o[4];
            lerp_cl_ax<32, 4>(dv, 32 >> lvl, lvl, px, py, pz, o);
            #pragma unroll
            for (int c = 0; c < 4; ++c) raw[(lvl * 4 + c) * RSTR + pg] = o[c];
        } else {
            raw[12 * RSTR + pg] = 0.f;
        }
    }
    wave_sync();

    // ---- Phase 2: embed deform -> X_d frags (kt 0..3, mt=w, mode-1) ----
    {
        float s0[4], c0[4];
        #pragma unroll
        for (int m = 0; m < 4; ++m) {
            float x = raw[min(cc + m, 12) * RSTR + pp];
            s0[m] = __sinf(x);
            c0[m] = __cosf(x);
        }
        #pragma unroll
        for (int g = 0; g < 4; ++g) {
            float vs[8];
            #pragma unroll
            for (int m = 0; m < 4; ++m) {
                int r = cc + m;
                bool lad = r < 12;
                int i0 = (2 * g) * 4 + (r - 12);
                int i1 = (2 * g + 1) * 4 + (r - 12);
                float r0 = raw[min(max(i0, 0), 12) * RSTR + pp];
                float r1 = raw[min(max(i1, 0), 12) * RSTR + pp];
                vs[m]     = lad ? s0[m] : r0;
                vs[4 + m] = lad ? c0[m] : r1;
            }
            union { unsigned u[4]; s16x8 v; } pk;
            pk.u[0] = packbf(vs[0], vs[1]);
            pk.u[1] = packbf(vs[2], vs[3]);
            pk.u[2] = packbf(vs[4], vs[5]);
            pk.u[3] = packbf(vs[6], vs[7]);
            *(s16x8*)&xfrag[swz(XF(g, w, lane))] = pk.v;
            if (g < 3) {
                #pragma unroll
                for (int m = 0; m < 4; ++m) {
                    float s2 = 2.f * s0[m] * c0[m];
                    float c2 = c0[m] * c0[m] - s0[m] * s0[m];
                    s0[m] = s2; c0[m] = c2;
                }
            }
        }
    }
    __syncthreads();   // all waves' X_d slices complete before cross-wave GEMM

    // ---- Phase 3: dMLP L1 (K=128; nt=w, sweep mt 0..3; hi/lo split) ----
    {
        f32x4 acc[4];
        float bias = db1[w * 16 + nl];
        #pragma unroll
        for (int mt = 0; mt < 4; ++mt) acc[mt] = (f32x4){bias, bias, bias, bias};
        #pragma unroll 1
        for (int kt = 0; kt < 4; ++kt) {
            s16x8 bh = *(const s16x8*)&dW1h[((w * 4 + kt) * 64 + lane) * 8];
            s16x8 bl = *(const s16x8*)&dW1l[((w * 4 + kt) * 64 + lane) * 8];
            #pragma unroll
            for (int mt = 0; mt < 4; ++mt) {
                s16x8 a = *(const s16x8*)&xfrag[swz(XF(kt, mt, lane))];
                acc[mt] = MFMA(a, bh, acc[mt]);
                acc[mt] = MFMA(a, bl, acc[mt]);
            }
        }
        // relu -> H_d frags (kt 4..5, disjoint from X_d kt 0..3)
        int j = w * 16 + nl;
        #pragma unroll
        for (int mt = 0; mt < 4; ++mt) {
            int a0 = fragAddr(mt * 16 + cc, 128 + j);
            #pragma unroll
            for (int i = 0; i < 4; ++i)
                xfrag[a0 ^ (8 * i)] = f2bf(fmaxf(acc[mt][i], 0.f));
        }
    }
    __syncthreads();   // all waves' H_d j-columns complete before ph4 reads

    // ---- Phase 4: dMLP L2 (K=64, H_d at kt 4..5; mt=w -> own points) ----
    {
        f32x4 acc = (f32x4){0, 0, 0, 0};
        #pragma unroll
        for (int kt = 0; kt < 2; ++kt) {
            s16x8 bb = *(const s16x8*)&dW2f[(kt * 64 + lane) * 8];
            s16x8 a = *(const s16x8*)&xfrag[swz(XF(4 + kt, w, lane))];
            acc = MFMA(a, bb, acc);
        }
        int col = nl;
        if (col < 3) {
            #pragma unroll
            for (int i = 0; i < 4; ++i) {
                int p = w * 16 + cc + i;
                float v = acc[i] + db2[col];
                out[(b * 3 + col) * NPTS + n0 + p] = v;
                dp[col * 64 + p] = fmaf(v, 0.1f, qpb[col * NPTS + n0 + p]);
            }
        }
    }
    wave_sync();   // dp for wave-own points only -> wave-local fence suffices

    // ---- Phase 5: feature interp (WAVE-PRIVATE, bf16 vol); viewdir lvl==3 ---
    {
        if (lvl < 3) {
            float px = dp[pg], py = dp[64 + pg], pz = dp[128 + pg];
            float o[8];
            if (CL) lerp_bf_ax64(fvt, 64 >> lvl, lvl, px, py, pz, o);
            else    lerp_cm_rt<64, 8>(fvol, 64 >> lvl, lvl, px, py, pz, o);
            #pragma unroll
            for (int c = 0; c < 8; ++c) raw[(lvl * 8 + c) * RSTR + pg] = o[c];
        } else {
            int n = n0 + pg;
            raw[24 * RSTR + pg] = qvb[n];
            raw[25 * RSTR + pg] = qvb[NPTS + n];
            raw[26 * RSTR + pg] = qvb[2 * NPTS + n];
            raw[27 * RSTR + pg] = 0.f;
        }
    }
    wave_sync();

    // ---- Phase 6: embed feature+view -> X frags (kt 0..7, mt=w, mode-2/3) --
    {
        float sL[4], cL[4], sH[4], cH[4];
        #pragma unroll
        for (int m = 0; m < 4; ++m) {
            float xl = raw[(cc + m) * RSTR + pp];
            sL[m] = __sinf(xl); cL[m] = __cosf(xl);
            float xh = raw[min(16 + cc + m, 27) * RSTR + pp];
            sH[m] = __sinf(xh); cH[m] = __cosf(xh);
        }
        #pragma unroll
        for (int g = 0; g < 4; ++g) {
            #pragma unroll
            for (int tg = 0; tg < 2; ++tg) {
                float vs[8];
                #pragma unroll
                for (int m = 0; m < 4; ++m) {
                    vs[m] = tg ? cL[m] : sL[m];
                    int rh = 16 + cc + m;
                    int idx = (2 * g + tg) * 5 + (rh - 27);
                    float rsv = raw[min(max(idx, 0), 27) * RSTR + pp];
                    float lad = tg ? cH[m] : sH[m];
                    vs[4 + m] = (rh < 27) ? lad : rsv;
                }
                union { unsigned u[4]; s16x8 v; } pk;
                pk.u[0] = packbf(vs[0], vs[1]);
                pk.u[1] = packbf(vs[2], vs[3]);
                pk.u[2] = packbf(vs[4], vs[5]);
                pk.u[3] = packbf(vs[6], vs[7]);
                *(s16x8*)&xfrag[swz(XF(2 * g + tg, w, lane))] = pk.v;
            }
            if (g < 3) {
                #pragma unroll
                for (int m = 0; m < 4; ++m) {
                    float s2 = 2.f * sL[m] * cL[m];
                    float c2 = cL[m] * cL[m] - sL[m] * sL[m];
                    sL[m] = s2; cL[m] = c2;
                    float s3 = 2.f * sH[m] * cH[m];
                    float c3 = cH[m] * cH[m] - sH[m] * sH[m];
                    sH[m] = s3; cH[m] = c3;
                }
            }
        }
    }
    __syncthreads();   // all waves' X slices complete before cross-wave GEMM

    // ---- Phase 7: density L1 (single bf16) + color L1 (nt pair = 2w,2w+1) --
    f32x4 accs[4][2], accc[4][2];
    {
        #pragma unroll
        for (int q = 0; q < 2; ++q) {
            float bsv = sHb[b * 128 + (2 * w + q) * 16 + nl];
            float bcv = cHb[b * 128 + (2 * w + q) * 16 + nl];
            #pragma unroll
            for (int mt = 0; mt < 4; ++mt) {
                accs[mt][q] = (f32x4){bsv, bsv, bsv, bsv};
                accc[mt][q] = (f32x4){bcv, bcv, bcv, bcv};
            }
        }
        #pragma unroll 1
        for (int kt = 0; kt < 8; ++kt) {
            s16x8 bh0 = *(const s16x8*)&sW1h[(((2 * w    ) * 8 + kt) * 64 + lane) * 8];
            s16x8 bh1 = *(const s16x8*)&sW1h[(((2 * w + 1) * 8 + kt) * 64 + lane) * 8];
            #pragma unroll
            for (int mt = 0; mt < 4; ++mt) {
                s16x8 a = *(const s16x8*)&xfrag[swz(XF(kt, mt, lane))];
                accs[mt][0] = MFMA(a, bh0, accs[mt][0]);
                accs[mt][1] = MFMA(a, bh1, accs[mt][1]);
            }
        }
        #pragma unroll 1
        for (int kt = 0; kt < 8; ++kt) {
            s16x8 b0 = *(const s16x8*)&cW1f[(((2 * w    ) * 8 + kt) * 64 + lane) * 8];
            s16x8 b1 = *(const s16x8*)&cW1f[(((2 * w + 1) * 8 + kt) * 64 + lane) * 8];
            #pragma unroll
            for (int mt = 0; mt < 4; ++mt) {
                s16x8 a = *(const s16x8*)&xfrag[swz(XF(kt, mt, lane))];
                accc[mt][0] = MFMA(a, b0, accc[mt][0]);
                accc[mt][1] = MFMA(a, b1, accc[mt][1]);
            }
        }
    }
    __syncthreads();   // all X reads done before H overwrites the same region

    // ---- Phase 8: relu -> H_s (kt 0..3) + H_c (kt 4..7), PAIRED b32 writes --
    // sigma layout (mode 4): h=(2w+q)*16+nl at kt=w, kk=2*nl+q -> (q0,q1) are
    // consecutive aligned j-elements of one fragment; swz keeps pairs intact.
    {
        const int jbase = ((nl >> 3) << 2) + ((nl & 1) << 1);
        const int lbase = ((nl & 7) >> 1) * 16 + cc;
        #pragma unroll
        for (int mt = 0; mt < 4; ++mt) {
            int a0 = swz((((w * 4 + mt) * 64) + lbase) * 8 + jbase);
            #pragma unroll
            for (int i = 0; i < 4; ++i) {
                int ai = a0 ^ (8 * i);
                float s0v = fmaxf(accs[mt][0][i], 0.f);
                float s1v = fmaxf(accs[mt][1][i], 0.f);
                float c0v = fmaxf(accc[mt][0][i], 0.f);
                float c1v = fmaxf(accc[mt][1][i], 0.f);
                *(unsigned*)&xfrag[ai]        = packbf(s0v, s1v);
                *(unsigned*)&xfrag[ai + 8192] = packbf(c0v, c1v);
            }
        }
    }
    __syncthreads();

    // ---- Phase 9: density L2 + color L2 (K=128 each; mt=w -> own points) ---
    {
        f32x4 as = (f32x4){0, 0, 0, 0};
        f32x4 ac = (f32x4){0, 0, 0, 0};
        #pragma unroll
        for (int kt = 0; kt < 4; ++kt) {
            s16x8 bsv = *(const s16x8*)&sW2f[(kt * 64 + lane) * 8];
            s16x8 bcv = *(const s16x8*)&cW2f[(kt * 64 + lane) * 8];
            s16x8 a1 = *(const s16x8*)&xfrag[swz(XF(kt, w, lane))];
            s16x8 a2 = *(const s16x8*)&xfrag[swz(XF(4 + kt, w, lane))];
            as = MFMA(a1, bsv, as);
            ac = MFMA(a2, bcv, ac);
        }
        int col = nl;
        #pragma unroll
        for (int i = 0; i < 4; ++i) {
            int p = w * 16 + cc + i;
            if (col == 0)
                out[6 * NPTS + b * NPTS + n0 + p] = as[i] + sb2[0];
            if (col < 3) {
                float v = ac[i] + cb2[col];
                out[8 * NPTS + (b * 3 + col) * NPTS + n0 + p] =
                    1.f / (1.f + __expf(-v));
            }
        }
    }
}

// ---------------------------------------------------------------------------
extern "C" void kernel_launch(void* const* d_in, const int* in_sizes, int n_in,
                              void* d_out, int out_size, void* d_ws, size_t ws_size,
                              hipStream_t stream) {
    const float* qp   = (const float*)d_in[0];
    const float* qv   = (const float*)d_in[1];
    const float* exp_ = (const float*)d_in[2];
    const float* bs   = (const float*)d_in[3];
    const float* mean = (const float*)d_in[4];
    const float* fvol = (const float*)d_in[5];
    const float* dW1  = (const float*)d_in[6];
    const float* db1  = (const float*)d_in[7];
    const float* dW2  = (const float*)d_in[8];
    const float* db2  = (const float*)d_in[9];
    const float* sW1  = (const float*)d_in[10];
    const float* sb1  = (const float*)d_in[11];
    const float* sW2  = (const float*)d_in[12];
    const float* sb2  = (const float*)d_in[13];
    const float* cW1  = (const float*)d_in[14];
    const float* cb1  = (const float*)d_in[15];
    const float* cW2  = (const float*)d_in[16];
    const float* cb2  = (const float*)d_in[17];

    float* out = (float*)d_out;
    float* ws  = (float*)d_ws;

    float* dvt = ws;                                   // 262144 f
    float* sHb = ws + 262144;                          // 256 f
    float* cHb = ws + 262400;                          // 256 f
    unsigned short* wb = (unsigned short*)(ws + 262656);
    unsigned short* dW1h  = wb;                        // 8192
    unsigned short* dW1l  = wb + 8192;                 // 8192
    unsigned short* sW1h  = wb + 16384;                // 32768
    unsigned short* cW1f_ = wb + 49152;                // 32768
    unsigned short* dW2f  = wb + 81920;                // 1024
    unsigned short* sW2f  = wb + 82944;                // 2048
    unsigned short* cW2f  = wb + 84992;                // 2048 (end 87040 u16)
    unsigned short* fvt = (unsigned short*)(ws + 306176);  // 2097152 u16 (4 MB)
    bool cl = ws_size >= (size_t)306176 * 4 + (size_t)2097152 * 2;

    k_deform_vol_t<<<1024, 256, 0, stream>>>(exp_, bs, mean, dvt);
    k_hb<<<2, 128, 0, stream>>>(exp_, sW1, sb1, cW1, cb1, sHb, cHb);
    k_wprep<<<32, 256, 0, stream>>>(dW1, dW1h, dW1l, 4, 64, 128, 1, 8192);
    k_wprep<<<128, 256, 0, stream>>>(sW1, sW1h, nullptr, 8, 128, 256, 2, 32768);
    k_wprep<<<128, 256, 0, stream>>>(cW1, cW1f_, nullptr, 8, 128, 256, 3, 32768);
    k_wprep<<<4, 256, 0, stream>>>(dW2, dW2f, nullptr, 2, 3, 64, 0, 1024);
    k_wprep<<<8, 256, 0, stream>>>(sW2, sW2f, nullptr, 4, 1, 128, 4, 2048);
    k_wprep<<<8, 256, 0, stream>>>(cW2, cW2f, nullptr, 4, 3, 128, 4, 2048);

    if (cl) {
        k_ftr_bf<<<2097152 / 256, 256, 0, stream>>>(fvol, fvt);
        k_main<true><<<8192, 256, 0, stream>>>(
            qp, qv, dvt, fvt, fvol, db1, db2, sb2, cb2, sHb, cHb,
            dW1h, dW1l, sW1h, cW1f_, dW2f, sW2f, cW2f, out);
    } else {
        k_main<false><<<8192, 256, 0, stream>>>(
            qp, qv, dvt, fvt, fvol, db1, db2, sb2, cb2, sHb, cHb,
            dW1h, dW1l, sW1h, cW1f_, dW2f, sW2f, cW2f, out);
    }
}

// Round 15
// 208.845 us; speedup vs baseline: 1.1858x; 1.0108x over previous
//
#include <hip/hip_runtime.h>
#include <math.h>

#define NPTS 262144
#define RSTR 66    // raw[] row stride in floats (64 pts + 2 pad)

typedef __attribute__((ext_vector_type(2))) float f32x2;
typedef __attribute__((ext_vector_type(4))) float f32x4;
typedef __attribute__((ext_vector_type(8))) short s16x8;

// Exact round-to-nearest-even f32->bf16 (matches numpy/JAX). Do NOT use
// v_cvt_pk_bf16_f32: proven non-RTNE by round-3/4/5 bisection.
__device__ __forceinline__ unsigned short f2bf(float f) {
    union { float f; unsigned u; } v; v.f = f;
    unsigned u = v.u;
    return (unsigned short)((u + 0x7fffu + ((u >> 16) & 1u)) >> 16);
}
__device__ __forceinline__ float bf2f(unsigned short h) {
    union { unsigned u; float f; } v; v.u = ((unsigned)h) << 16;
    return v.f;
}
__device__ __forceinline__ unsigned rnd16(float f) {
    union { float f; unsigned u; } v; v.f = f;
    return v.u + 0x7fffu + ((v.u >> 16) & 1u);
}
__device__ __forceinline__ unsigned packbf(float lo, float hi) {
#if defined(__has_builtin)
#if __has_builtin(__builtin_amdgcn_perm)
    return __builtin_amdgcn_perm(rnd16(hi), rnd16(lo), 0x07060302u);
#else
    return (rnd16(hi) & 0xffff0000u) | (rnd16(lo) >> 16);
#endif
#else
    return (rnd16(hi) & 0xffff0000u) | (rnd16(lo) >> 16);
#endif
}

// Packed dual-f32 FMA (v_pk_fma_f32 on CDNA). IEEE fma per lane ->
// bit-exact vs two fmaf. Scalar fallback if builtin unavailable.
__device__ __forceinline__ f32x2 pkfma(f32x2 a, f32x2 b, f32x2 c) {
#if defined(__has_builtin)
#if __has_builtin(__builtin_elementwise_fma)
    return __builtin_elementwise_fma(a, b, c);
#else
    return (f32x2){fmaf(a.x, b.x, c.x), fmaf(a.y, b.y, c.y)};
#endif
#else
    return (f32x2){fmaf(a.x, b.x, c.x), fmaf(a.y, b.y, c.y)};
#endif
}
__device__ __forceinline__ float asf(unsigned u) {
    union { unsigned u; float f; } v; v.u = u; return v.f;
}

// Wave-local LDS fence for wave-private producer->consumer chains.
__device__ __forceinline__ void wave_sync() {
    __builtin_amdgcn_sched_barrier(0);
    asm volatile("s_waitcnt lgkmcnt(0)" ::: "memory");
    __builtin_amdgcn_sched_barrier(0);
}

// xfrag element-address swizzle: inject bits 7,8 into bank bits 3,4.
// Only bits >=3 touched -> b128/b32-safe; applied to ALL xfrag accesses.
__device__ __forceinline__ int swz(int e) {
    return e ^ (((e >> 7) & 1) << 3) ^ (((e >> 8) & 1) << 4);
}

// Linear fragment base (bf16-element units): [kt=8][mt=4][lane=64][j=8]
__device__ __forceinline__ int XF(int kt, int mt, int lane) {
    return ((kt * 4 + mt) * 64 + lane) * 8;
}

// A-fragment scatter address (swizzled) for mfma_f32_16x16x32_bf16.
// CSE identities: fragAddr(p0+i,k) = fragAddr(p0,k) ^ (8*i)  (XOR, not add!);
//                 fragAddr(p,128+j) = fragAddr(p,j) + 8192   (carry-free).
__device__ __forceinline__ int fragAddr(int p, int k) {
    int kt = k >> 5, kk = k & 31;
    int lane = (((kk & 15) >> 2) << 4) | (p & 15);
    int j = ((kk >> 4) << 2) | (kk & 3);
    int mt = (p >> 4) & 3;
    return swz((((kt * 4 + mt) * 64) + lane) * 8 + j);
}

// ---------------------------------------------------------------------------
__global__ void k_deform_vol_t(const float* __restrict__ exp_,
                               const float* __restrict__ bs,
                               const float* __restrict__ mean,
                               float* __restrict__ dvt) {
    int idx = blockIdx.x * blockDim.x + threadIdx.x;   // 262144
    int c = idx & 3;
    int v = (idx >> 2) & 32767;
    int b = idx >> 17;
    float acc = mean[c * 32768 + v];
    #pragma unroll 8
    for (int e = 0; e < 32; ++e)
        acc = fmaf(exp_[b * 32 + e], bs[(e * 4 + c) * 32768 + v], acc);
    dvt[idx] = acc;
}

// feature volume transpose + bf16 quantize: fvt[v][c] = bf16(fvol[c][v]).
// 4 MB -> L2-resident per XCD; one 16B load covers all 8 channels.
__global__ void k_ftr_bf(const float* __restrict__ fvol,
                         unsigned short* __restrict__ fvt) {
    int i = blockIdx.x * blockDim.x + threadIdx.x;     // 2097152
    int c = i >> 18;
    int v = i & 262143;
    fvt[v * 8 + c] = f2bf(fvol[i]);
}

__global__ void k_hb(const float* __restrict__ exp_,
                     const float* __restrict__ sW1, const float* __restrict__ sb1,
                     const float* __restrict__ cW1, const float* __restrict__ cb1,
                     float* __restrict__ sHb, float* __restrict__ cHb) {
    int b = blockIdx.x;
    int j = threadIdx.x;           // 128
    float a = sb1[j];
    float a2 = cb1[j];
    for (int e = 0; e < 32; ++e) {
        float ev = exp_[b * 32 + e] * (1.0f / 3.0f);
        a  = fmaf(ev, sW1[(216 + e) * 128 + j], a);
        a2 = fmaf(ev, cW1[(243 + e) * 128 + j], a2);
    }
    sHb[b * 128 + j] = a;
    cHb[b * 128 + j] = a2;
}

// ---------------------------------------------------------------------------
// Weight -> B-fragment tables (bf16, optional hi/lo split). Layout [nt][kt].
//  mode 0: identity
//  mode 1 (dW1, K=128): permuted deform K mapping (round-7 derivation)
//  mode 2/3 (sW1/cW1, K=256): permuted feature K mapping
//  mode 4 (sW2/cW2, K=128): H sigma-layout -> h = 32*kt + 16*(kk&1) + (kk>>1)
// ---------------------------------------------------------------------------
__global__ void k_wprep(const float* __restrict__ src,
                        unsigned short* __restrict__ dhi,
                        unsigned short* __restrict__ dlo,
                        int KT, int Nsrc, int Ksrc, int mode, int total) {
    int i = blockIdx.x * 256 + threadIdx.x;
    if (i >= total) return;
    int j = i & 7, lane = (i >> 3) & 63;
    int tile = i >> 9;
    int kt = tile % KT, nt = tile / KT;
    int n = nt * 16 + (lane & 15);
    int k = kt * 32 + ((lane >> 4) << 2) + (j & 3) + ((j >> 2) << 4);
    int row = -1;
    if (mode == 0) {
        row = (k < Ksrc) ? k : -1;
    } else if (mode == 1) {
        int g = k >> 5, tg = (k >> 4) & 1, r = k & 15;
        if (r < 12) row = 12 + 24 * g + 12 * tg + r;
        else { int idx = (2 * g + tg) * 4 + (r - 12); row = (idx < 12) ? idx : -1; }
    } else if (mode == 4) {
        int kk = k & 31;
        row = (k >> 5) * 32 + ((kk & 1) << 4) + (kk >> 1);
        if (row >= Ksrc) row = -1;
    } else {
        int g = k >> 6, tg = (k >> 5) & 1, r = k & 31;
        if (r < 24) row = 24 + 48 * g + 24 * tg + r;
        else if (r < 27) row = (mode == 3) ? 219 + 6 * g + 3 * tg + (r - 24) : -1;
        else {
            int idx = (2 * g + tg) * 5 + (r - 27);
            if (idx < 24) row = idx;
            else if (idx < 27 && mode == 3) row = 216 + (idx - 24);
            else row = -1;
        }
    }
    float v = (row >= 0 && n < Nsrc) ? src[row * Nsrc + n] : 0.0f;
    unsigned short h = f2bf(v);
    dhi[i] = h;
    if (dlo) dlo[i] = f2bf(v - bf2f(h));
}

// ---------------------------------------------------------------------------
// Axis-factored trilinear gather, f32 channels-last, packed-FMA accumulate.
// ---------------------------------------------------------------------------
template<int DIM, int NC>
__device__ __forceinline__ void lerp_cl_ax(const float* __restrict__ vol,
                                           int S, int lc,
                                           float px, float py, float pz,
                                           float* __restrict__ o) {
    float fS = (float)S;
    float fx = px * fS - 0.5f;
    float fy = py * fS - 0.5f;
    float fz = pz * fS - 0.5f;
    float x0 = floorf(fx), y0 = floorf(fy), z0 = floorf(fz);
    float wx = fx - x0, wy = fy - y0, wz = fz - z0;
    int ix = (int)x0, iy = (int)y0, iz = (int)z0;
    float wxa[2], wya[2], wza[2];
    int   oxa[2], oya[2], oza[2];
    #pragma unroll
    for (int d = 0; d < 2; ++d) {
        int xi = ix + d, yi = iy + d, zi = iz + d;
        wxa[d] = (xi >= 0 && xi < S) ? (d ? wx : 1.f - wx) : 0.f;
        wya[d] = (yi >= 0 && yi < S) ? (d ? wy : 1.f - wy) : 0.f;
        wza[d] = (zi >= 0 && zi < S) ? (d ? wz : 1.f - wz) : 0.f;
        oxa[d] = (min(max(xi, 0), S - 1) << lc) * NC;
        oya[d] = ((min(max(yi, 0), S - 1) << lc) * DIM) * NC;
        oza[d] = ((min(max(zi, 0), S - 1) << lc) * DIM * DIM) * NC;
    }
    f32x2 a2[NC / 2];
    #pragma unroll
    for (int c = 0; c < NC / 2; ++c) a2[c] = (f32x2){0.f, 0.f};
    #pragma unroll
    for (int dz = 0; dz < 2; ++dz)
    #pragma unroll
    for (int dy = 0; dy < 2; ++dy) {
        float wzy = wza[dz] * wya[dy];
        int ozy = oza[dz] + oya[dy];
        #pragma unroll
        for (int dx = 0; dx < 2; ++dx) {
            float wgt = wzy * wxa[dx];
            f32x2 w2 = (f32x2){wgt, wgt};
            const float4* q = (const float4*)(vol + (size_t)(ozy + oxa[dx]));
            float4 v0 = q[0];
            a2[0] = pkfma((f32x2){v0.x, v0.y}, w2, a2[0]);
            a2[1] = pkfma((f32x2){v0.z, v0.w}, w2, a2[1]);
            if (NC == 8) {
                float4 v1 = q[1];
                a2[2] = pkfma((f32x2){v1.x, v1.y}, w2, a2[2]);
                a2[3] = pkfma((f32x2){v1.z, v1.w}, w2, a2[3]);
            }
        }
    }
    #pragma unroll
    for (int c = 0; c < NC / 2; ++c) { o[2 * c] = a2[c].x; o[2 * c + 1] = a2[c].y; }
}

// Axis-factored gather over the bf16 channels-last feature volume.
// One s16x8 load per corner; channel pairs expand via 2 bit-ops + 1 pk_fma.
__device__ __forceinline__ void lerp_bf_ax64(const unsigned short* __restrict__ vol,
                                             int S, int lc,
                                             float px, float py, float pz,
                                             float* __restrict__ o) {
    const int DIM = 64, NC = 8;
    float fS = (float)S;
    float fx = px * fS - 0.5f;
    float fy = py * fS - 0.5f;
    float fz = pz * fS - 0.5f;
    float x0 = floorf(fx), y0 = floorf(fy), z0 = floorf(fz);
    float wx = fx - x0, wy = fy - y0, wz = fz - z0;
    int ix = (int)x0, iy = (int)y0, iz = (int)z0;
    float wxa[2], wya[2], wza[2];
    int   oxa[2], oya[2], oza[2];
    #pragma unroll
    for (int d = 0; d < 2; ++d) {
        int xi = ix + d, yi = iy + d, zi = iz + d;
        wxa[d] = (xi >= 0 && xi < S) ? (d ? wx : 1.f - wx) : 0.f;
        wya[d] = (yi >= 0 && yi < S) ? (d ? wy : 1.f - wy) : 0.f;
        wza[d] = (zi >= 0 && zi < S) ? (d ? wz : 1.f - wz) : 0.f;
        oxa[d] = (min(max(xi, 0), S - 1) << lc) * NC;
        oya[d] = ((min(max(yi, 0), S - 1) << lc) * DIM) * NC;
        oza[d] = ((min(max(zi, 0), S - 1) << lc) * DIM * DIM) * NC;
    }
    f32x2 a2[4];
    #pragma unroll
    for (int c = 0; c < 4; ++c) a2[c] = (f32x2){0.f, 0.f};
    #pragma unroll
    for (int dz = 0; dz < 2; ++dz)
    #pragma unroll
    for (int dy = 0; dy < 2; ++dy) {
        float wzy = wza[dz] * wya[dy];
        int ozy = oza[dz] + oya[dy];
        #pragma unroll
        for (int dx = 0; dx < 2; ++dx) {
            float wgt = wzy * wxa[dx];
            f32x2 w2 = (f32x2){wgt, wgt};
            union { s16x8 v; unsigned u[4]; } q;
            q.v = *(const s16x8*)(vol + (size_t)(ozy + oxa[dx]));
            #pragma unroll
            for (int c = 0; c < 4; ++c) {
                f32x2 pv = (f32x2){asf(q.u[c] << 16), asf(q.u[c] & 0xffff0000u)};
                a2[c] = pkfma(pv, w2, a2[c]);
            }
        }
    }
    #pragma unroll
    for (int c = 0; c < 4; ++c) { o[2 * c] = a2[c].x; o[2 * c + 1] = a2[c].y; }
}

// channel-major f32 fallback (only used when ws too small for fvt)
template<int DIM, int NC>
__device__ __forceinline__ void lerp_cm_rt(const float* __restrict__ vol,
                                           int S, int lc,
                                           float px, float py, float pz,
                                           float* __restrict__ o) {
    float fS = (float)S;
    float fx = px * fS - 0.5f;
    float fy = py * fS - 0.5f;
    float fz = pz * fS - 0.5f;
    float x0 = floorf(fx), y0 = floorf(fy), z0 = floorf(fz);
    float wx = fx - x0, wy = fy - y0, wz = fz - z0;
    int ix = (int)x0, iy = (int)y0, iz = (int)z0;
    #pragma unroll
    for (int c = 0; c < NC; ++c) o[c] = 0.0f;
    #pragma unroll
    for (int dz = 0; dz < 2; ++dz)
    #pragma unroll
    for (int dy = 0; dy < 2; ++dy)
    #pragma unroll
    for (int dx = 0; dx < 2; ++dx) {
        int xi = ix + dx, yi = iy + dy, zi = iz + dz;
        bool valid = (xi >= 0) & (xi < S) & (yi >= 0) & (yi < S) & (zi >= 0) & (zi < S);
        int xc = min(max(xi, 0), S - 1);
        int yc = min(max(yi, 0), S - 1);
        int zc = min(max(zi, 0), S - 1);
        float wgt = (dz ? wz : 1.f - wz) * (dy ? wy : 1.f - wy) * (dx ? wx : 1.f - wx);
        wgt = valid ? wgt : 0.f;
        int off = ((zc << lc) * DIM + (yc << lc)) * DIM + (xc << lc);
        #pragma unroll
        for (int c = 0; c < NC; ++c)
            o[c] = fmaf(vol[c * (DIM * DIM * DIM) + off], wgt, o[c]);
    }
}

#define MFMA(a, b, c) __builtin_amdgcn_mfma_f32_16x16x32_bf16((a), (b), (c), 0, 0, 0)

// ---------------------------------------------------------------------------
// Main fused kernel: 64 points / block, 4 waves. Hybrid sync (5 barriers +
// wave-local fences). bf16 L2-resident feature volume; packed-f32 gathers;
// viewdir loads hoisted to phase 1 (rows 24..27 untouched by ph2..4).
// Math bit-exact vs round 14.
// ---------------------------------------------------------------------------
template<bool CL>
__global__ __launch_bounds__(256, 4) void k_main(
    const float* __restrict__ qp, const float* __restrict__ qv,
    const float* __restrict__ dvt,
    const unsigned short* __restrict__ fvt, const float* __restrict__ fvol,
    const float* __restrict__ db1, const float* __restrict__ db2,
    const float* __restrict__ sb2, const float* __restrict__ cb2,
    const float* __restrict__ sHb, const float* __restrict__ cHb,
    const unsigned short* __restrict__ dW1h, const unsigned short* __restrict__ dW1l,
    const unsigned short* __restrict__ sW1h,
    const unsigned short* __restrict__ cW1f,
    const unsigned short* __restrict__ dW2f, const unsigned short* __restrict__ sW2f,
    const unsigned short* __restrict__ cW2f,
    float* __restrict__ out)
{
    __shared__ __align__(16) unsigned short xfrag[16384];    // 32 KB (8 kt)
    __shared__ __align__(16) float raw[28 * RSTR];           // 7.4 KB
    __shared__ float dp[3 * 64];                             // 0.75 KB

    const int t = threadIdx.x;
    const int lane = t & 63;
    const int w = t >> 6;
    const int gp0 = blockIdx.x * 64;
    const int b = gp0 / NPTS;
    const int n0 = gp0 - b * NPTS;
    const float* qpb = qp + b * 3 * NPTS;
    const float* qvb = qv + b * 3 * NPTS;

    const int cc = (lane >> 4) << 2;       // 0,4,8,12
    const int nl = lane & 15;
    const int pp = w * 16 + nl;            // embed point col (wave-private)
    const int lvl = lane >> 4;             // gather: level (3 = aux duty)
    const int pg = w * 16 + nl;            // gather point col (wave-private)

    // ---- Phase 1: deform interp (WAVE-PRIVATE). lvl==3 lanes: zero rows
    //      12/27 + HOISTED viewdir rows 24..26 (untouched until ph6). ----
    {
        const float* dv = dvt + b * 131072;
        if (lvl < 3) {
            int n = n0 + pg;
            float px = qpb[n], py = qpb[NPTS + n], pz = qpb[2 * NPTS + n];
            float o[4];
            lerp_cl_ax<32, 4>(dv, 32 >> lvl, lvl, px, py, pz, o);
            #pragma unroll
            for (int c = 0; c < 4; ++c) raw[(lvl * 4 + c) * RSTR + pg] = o[c];
        } else {
            int n = n0 + pg;
            raw[12 * RSTR + pg] = 0.f;
            raw[24 * RSTR + pg] = qvb[n];
            raw[25 * RSTR + pg] = qvb[NPTS + n];
            raw[26 * RSTR + pg] = qvb[2 * NPTS + n];
            raw[27 * RSTR + pg] = 0.f;
        }
    }
    wave_sync();

    // ---- Phase 2: embed deform -> X_d frags (kt 0..3, mt=w, mode-1) ----
    {
        float s0[4], c0[4];
        #pragma unroll
        for (int m = 0; m < 4; ++m) {
            float x = raw[min(cc + m, 12) * RSTR + pp];
            s0[m] = __sinf(x);
            c0[m] = __cosf(x);
        }
        #pragma unroll
        for (int g = 0; g < 4; ++g) {
            float vs[8];
            #pragma unroll
            for (int m = 0; m < 4; ++m) {
                int r = cc + m;
                bool lad = r < 12;
                int i0 = (2 * g) * 4 + (r - 12);
                int i1 = (2 * g + 1) * 4 + (r - 12);
                float r0 = raw[min(max(i0, 0), 12) * RSTR + pp];
                float r1 = raw[min(max(i1, 0), 12) * RSTR + pp];
                vs[m]     = lad ? s0[m] : r0;
                vs[4 + m] = lad ? c0[m] : r1;
            }
            union { unsigned u[4]; s16x8 v; } pk;
            pk.u[0] = packbf(vs[0], vs[1]);
            pk.u[1] = packbf(vs[2], vs[3]);
            pk.u[2] = packbf(vs[4], vs[5]);
            pk.u[3] = packbf(vs[6], vs[7]);
            *(s16x8*)&xfrag[swz(XF(g, w, lane))] = pk.v;
            if (g < 3) {
                #pragma unroll
                for (int m = 0; m < 4; ++m) {
                    float s2 = 2.f * s0[m] * c0[m];
                    float c2 = c0[m] * c0[m] - s0[m] * s0[m];
                    s0[m] = s2; c0[m] = c2;
                }
            }
        }
    }
    __syncthreads();   // all waves' X_d slices complete before cross-wave GEMM

    // ---- Phase 3: dMLP L1 (K=128; nt=w, sweep mt 0..3; hi/lo split) ----
    {
        f32x4 acc[4];
        float bias = db1[w * 16 + nl];
        #pragma unroll
        for (int mt = 0; mt < 4; ++mt) acc[mt] = (f32x4){bias, bias, bias, bias};
        #pragma unroll 1
        for (int kt = 0; kt < 4; ++kt) {
            s16x8 bh = *(const s16x8*)&dW1h[((w * 4 + kt) * 64 + lane) * 8];
            s16x8 bl = *(const s16x8*)&dW1l[((w * 4 + kt) * 64 + lane) * 8];
            #pragma unroll
            for (int mt = 0; mt < 4; ++mt) {
                s16x8 a = *(const s16x8*)&xfrag[swz(XF(kt, mt, lane))];
                acc[mt] = MFMA(a, bh, acc[mt]);
                acc[mt] = MFMA(a, bl, acc[mt]);
            }
        }
        // relu -> H_d frags (kt 4..5, disjoint from X_d kt 0..3)
        int j = w * 16 + nl;
        #pragma unroll
        for (int mt = 0; mt < 4; ++mt) {
            int a0 = fragAddr(mt * 16 + cc, 128 + j);
            #pragma unroll
            for (int i = 0; i < 4; ++i)
                xfrag[a0 ^ (8 * i)] = f2bf(fmaxf(acc[mt][i], 0.f));
        }
    }
    __syncthreads();   // all waves' H_d j-columns complete before ph4 reads

    // ---- Phase 4: dMLP L2 (K=64, H_d at kt 4..5; mt=w -> own points) ----
    {
        f32x4 acc = (f32x4){0, 0, 0, 0};
        #pragma unroll
        for (int kt = 0; kt < 2; ++kt) {
            s16x8 bb = *(const s16x8*)&dW2f[(kt * 64 + lane) * 8];
            s16x8 a = *(const s16x8*)&xfrag[swz(XF(4 + kt, w, lane))];
            acc = MFMA(a, bb, acc);
        }
        int col = nl;
        if (col < 3) {
            #pragma unroll
            for (int i = 0; i < 4; ++i) {
                int p = w * 16 + cc + i;
                float v = acc[i] + db2[col];
                out[(b * 3 + col) * NPTS + n0 + p] = v;
                dp[col * 64 + p] = fmaf(v, 0.1f, qpb[col * NPTS + n0 + p]);
            }
        }
    }
    wave_sync();   // dp for wave-own points only -> wave-local fence suffices

    // ---- Phase 5: feature interp (WAVE-PRIVATE, bf16 vol); lvl==3 idle ----
    {
        if (lvl < 3) {
            float px = dp[pg], py = dp[64 + pg], pz = dp[128 + pg];
            float o[8];
            if (CL) lerp_bf_ax64(fvt, 64 >> lvl, lvl, px, py, pz, o);
            else    lerp_cm_rt<64, 8>(fvol, 64 >> lvl, lvl, px, py, pz, o);
            #pragma unroll
            for (int c = 0; c < 8; ++c) raw[(lvl * 8 + c) * RSTR + pg] = o[c];
        }
    }
    wave_sync();

    // ---- Phase 6: embed feature+view -> X frags (kt 0..7, mt=w, mode-2/3) --
    {
        float sL[4], cL[4], sH[4], cH[4];
        #pragma unroll
        for (int m = 0; m < 4; ++m) {
            float xl = raw[(cc + m) * RSTR + pp];
            sL[m] = __sinf(xl); cL[m] = __cosf(xl);
            float xh = raw[min(16 + cc + m, 27) * RSTR + pp];
            sH[m] = __sinf(xh); cH[m] = __cosf(xh);
        }
        #pragma unroll
        for (int g = 0; g < 4; ++g) {
            #pragma unroll
            for (int tg = 0; tg < 2; ++tg) {
                float vs[8];
                #pragma unroll
                for (int m = 0; m < 4; ++m) {
                    vs[m] = tg ? cL[m] : sL[m];
                    int rh = 16 + cc + m;
                    int idx = (2 * g + tg) * 5 + (rh - 27);
                    float rsv = raw[min(max(idx, 0), 27) * RSTR + pp];
                    float lad = tg ? cH[m] : sH[m];
                    vs[4 + m] = (rh < 27) ? lad : rsv;
                }
                union { unsigned u[4]; s16x8 v; } pk;
                pk.u[0] = packbf(vs[0], vs[1]);
                pk.u[1] = packbf(vs[2], vs[3]);
                pk.u[2] = packbf(vs[4], vs[5]);
                pk.u[3] = packbf(vs[6], vs[7]);
                *(s16x8*)&xfrag[swz(XF(2 * g + tg, w, lane))] = pk.v;
            }
            if (g < 3) {
                #pragma unroll
                for (int m = 0; m < 4; ++m) {
                    float s2 = 2.f * sL[m] * cL[m];
                    float c2 = cL[m] * cL[m] - sL[m] * sL[m];
                    sL[m] = s2; cL[m] = c2;
                    float s3 = 2.f * sH[m] * cH[m];
                    float c3 = cH[m] * cH[m] - sH[m] * sH[m];
                    sH[m] = s3; cH[m] = c3;
                }
            }
        }
    }
    __syncthreads();   // all waves' X slices complete before cross-wave GEMM

    // ---- Phase 7: density L1 (single bf16) + color L1 (nt pair = 2w,2w+1) --
    f32x4 accs[4][2], accc[4][2];
    {
        #pragma unroll
        for (int q = 0; q < 2; ++q) {
            float bsv = sHb[b * 128 + (2 * w + q) * 16 + nl];
            float bcv = cHb[b * 128 + (2 * w + q) * 16 + nl];
            #pragma unroll
            for (int mt = 0; mt < 4; ++mt) {
                accs[mt][q] = (f32x4){bsv, bsv, bsv, bsv};
                accc[mt][q] = (f32x4){bcv, bcv, bcv, bcv};
            }
        }
        #pragma unroll 1
        for (int kt = 0; kt < 8; ++kt) {
            s16x8 bh0 = *(const s16x8*)&sW1h[(((2 * w    ) * 8 + kt) * 64 + lane) * 8];
            s16x8 bh1 = *(const s16x8*)&sW1h[(((2 * w + 1) * 8 + kt) * 64 + lane) * 8];
            #pragma unroll
            for (int mt = 0; mt < 4; ++mt) {
                s16x8 a = *(const s16x8*)&xfrag[swz(XF(kt, mt, lane))];
                accs[mt][0] = MFMA(a, bh0, accs[mt][0]);
                accs[mt][1] = MFMA(a, bh1, accs[mt][1]);
            }
        }
        #pragma unroll 1
        for (int kt = 0; kt < 8; ++kt) {
            s16x8 b0 = *(const s16x8*)&cW1f[(((2 * w    ) * 8 + kt) * 64 + lane) * 8];
            s16x8 b1 = *(const s16x8*)&cW1f[(((2 * w + 1) * 8 + kt) * 64 + lane) * 8];
            #pragma unroll
            for (int mt = 0; mt < 4; ++mt) {
                s16x8 a = *(const s16x8*)&xfrag[swz(XF(kt, mt, lane))];
                accc[mt][0] = MFMA(a, b0, accc[mt][0]);
                accc[mt][1] = MFMA(a, b1, accc[mt][1]);
            }
        }
    }
    __syncthreads();   // all X reads done before H overwrites the same region

    // ---- Phase 8: relu -> H_s (kt 0..3) + H_c (kt 4..7), PAIRED b32 writes --
    {
        const int jbase = ((nl >> 3) << 2) + ((nl & 1) << 1);
        const int lbase = ((nl & 7) >> 1) * 16 + cc;
        #pragma unroll
        for (int mt = 0; mt < 4; ++mt) {
            int a0 = swz((((w * 4 + mt) * 64) + lbase) * 8 + jbase);
            #pragma unroll
            for (int i = 0; i < 4; ++i) {
                int ai = a0 ^ (8 * i);
                float s0v = fmaxf(accs[mt][0][i], 0.f);
                float s1v = fmaxf(accs[mt][1][i], 0.f);
                float c0v = fmaxf(accc[mt][0][i], 0.f);
                float c1v = fmaxf(accc[mt][1][i], 0.f);
                *(unsigned*)&xfrag[ai]        = packbf(s0v, s1v);
                *(unsigned*)&xfrag[ai + 8192] = packbf(c0v, c1v);
            }
        }
    }
    __syncthreads();

    // ---- Phase 9: density L2 + color L2 (K=128 each; mt=w -> own points) ---
    {
        f32x4 as = (f32x4){0, 0, 0, 0};
        f32x4 ac = (f32x4){0, 0, 0, 0};
        #pragma unroll
        for (int kt = 0; kt < 4; ++kt) {
            s16x8 bsv = *(const s16x8*)&sW2f[(kt * 64 + lane) * 8];
            s16x8 bcv = *(const s16x8*)&cW2f[(kt * 64 + lane) * 8];
            s16x8 a1 = *(const s16x8*)&xfrag[swz(XF(kt, w, lane))];
            s16x8 a2 = *(const s16x8*)&xfrag[swz(XF(4 + kt, w, lane))];
            as = MFMA(a1, bsv, as);
            ac = MFMA(a2, bcv, ac);
        }
        int col = nl;
        #pragma unroll
        for (int i = 0; i < 4; ++i) {
            int p = w * 16 + cc + i;
            if (col == 0)
                out[6 * NPTS + b * NPTS + n0 + p] = as[i] + sb2[0];
            if (col < 3) {
                float v = ac[i] + cb2[col];
                out[8 * NPTS + (b * 3 + col) * NPTS + n0 + p] =
                    1.f / (1.f + __expf(-v));
            }
        }
    }
}

// ---------------------------------------------------------------------------
extern "C" void kernel_launch(void* const* d_in, const int* in_sizes, int n_in,
                              void* d_out, int out_size, void* d_ws, size_t ws_size,
                              hipStream_t stream) {
    const float* qp   = (const float*)d_in[0];
    const float* qv   = (const float*)d_in[1];
    const float* exp_ = (const float*)d_in[2];
    const float* bs   = (const float*)d_in[3];
    const float* mean = (const float*)d_in[4];
    const float* fvol = (const float*)d_in[5];
    const float* dW1  = (const float*)d_in[6];
    const float* db1  = (const float*)d_in[7];
    const float* dW2  = (const float*)d_in[8];
    const float* db2  = (const float*)d_in[9];
    const float* sW1  = (const float*)d_in[10];
    const float* sb1  = (const float*)d_in[11];
    const float* sW2  = (const float*)d_in[12];
    const float* sb2  = (const float*)d_in[13];
    const float* cW1  = (const float*)d_in[14];
    const float* cb1  = (const float*)d_in[15];
    const float* cW2  = (const float*)d_in[16];
    const float* cb2  = (const float*)d_in[17];

    float* out = (float*)d_out;
    float* ws  = (float*)d_ws;

    float* dvt = ws;                                   // 262144 f
    float* sHb = ws + 262144;                          // 256 f
    float* cHb = ws + 262400;                          // 256 f
    unsigned short* wb = (unsigned short*)(ws + 262656);
    unsigned short* dW1h  = wb;                        // 8192
    unsigned short* dW1l  = wb + 8192;                 // 8192
    unsigned short* sW1h  = wb + 16384;                // 32768
    unsigned short* cW1f_ = wb + 49152;                // 32768
    unsigned short* dW2f  = wb + 81920;                // 1024
    unsigned short* sW2f  = wb + 82944;                // 2048
    unsigned short* cW2f  = wb + 84992;                // 2048 (end 87040 u16)
    unsigned short* fvt = (unsigned short*)(ws + 306176);  // 2097152 u16 (4 MB)
    bool cl = ws_size >= (size_t)306176 * 4 + (size_t)2097152 * 2;

    k_deform_vol_t<<<1024, 256, 0, stream>>>(exp_, bs, mean, dvt);
    k_hb<<<2, 128, 0, stream>>>(exp_, sW1, sb1, cW1, cb1, sHb, cHb);
    k_wprep<<<32, 256, 0, stream>>>(dW1, dW1h, dW1l, 4, 64, 128, 1, 8192);
    k_wprep<<<128, 256, 0, stream>>>(sW1, sW1h, nullptr, 8, 128, 256, 2, 32768);
    k_wprep<<<128, 256, 0, stream>>>(cW1, cW1f_, nullptr, 8, 128, 256, 3, 32768);
    k_wprep<<<4, 256, 0, stream>>>(dW2, dW2f, nullptr, 2, 3, 64, 0, 1024);
    k_wprep<<<8, 256, 0, stream>>>(sW2, sW2f, nullptr, 4, 1, 128, 4, 2048);
    k_wprep<<<8, 256, 0, stream>>>(cW2, cW2f, nullptr, 4, 3, 128, 4, 2048);

    if (cl) {
        k_ftr_bf<<<2097152 / 256, 256, 0, stream>>>(fvol, fvt);
        k_main<true><<<8192, 256, 0, stream>>>(
            qp, qv, dvt, fvt, fvol, db1, db2, sb2, cb2, sHb, cHb,
            dW1h, dW1l, sW1h, cW1f_, dW2f, sW2f, cW2f, out);
    } else {
        k_main<false><<<8192, 256, 0, stream>>>(
            qp, qv, dvt, fvt, fvol, db1, db2, sb2, cb2, sHb, cHb,
            dW1h, dW1l, sW1h, cW1f_, dW2f, sW2f, cW2f, out);
    }
}